// Round 8
// baseline (236.950 us; speedup 1.0000x reference)
//
#include <hip/hip_runtime.h>
#include <hip/hip_bf16.h>
#include <math.h>

#define BATCH     256
#define DMODEL    2048
#define DSTATE    128
#define HEADDIM_  64
#define DINNER    4096
#define NHEADS_   64
#define CONVDIM   4352
#define DINPROJ   8512
#define EPS_      1e-5f

typedef __attribute__((ext_vector_type(8))) short short8;
typedef __attribute__((ext_vector_type(4))) short short4v;
typedef __attribute__((ext_vector_type(4))) float f32x4;

__device__ __forceinline__ short bfbits(float f) {
    __hip_bfloat16 h = __float2bfloat16(f);
    return *reinterpret_cast<short*>(&h);
}
__device__ __forceinline__ short8 cvt8(float4 a, float4 b) {
    short8 r;
    r[0] = bfbits(a.x); r[1] = bfbits(a.y); r[2] = bfbits(a.z); r[3] = bfbits(a.w);
    r[4] = bfbits(b.x); r[5] = bfbits(b.y); r[6] = bfbits(b.z); r[7] = bfbits(b.w);
    return r;
}

// ---------------- f32 -> bf16 pre-convert (hid) ----------------
__global__ __launch_bounds__(256)
void f2b(const float* __restrict__ in, short* __restrict__ o) {
    int i = (blockIdx.x * 256 + threadIdx.x) * 8;
    float4 a = *(const float4*)(in + i);
    float4 b = *(const float4*)(in + i + 4);
    *(short8*)(o + i) = cvt8(a, b);
}

// ---------- bf16 MFMA GEMM: C[256][N] = A[256][K](bf16) * W[N][K]^T(f32) ----------
// BM=256, BN=64, BK=128. 512 thr = 8 waves (4m x 2n), wave tile 64x32.
// A-fragments read DIRECTLY from global (A is 1-2 MB -> L2-resident); only B
// staged in LDS (dbuf 2x16KB, 256B rows, XOR-swizzle ^(row&15)<<4).
// All global loads issued AFTER the barrier (cheap vmcnt drain at barrier).
// grid=(N/64, 1, ksplit); ATOMIC: accumulate into C via unsafeAtomicAdd.
template<bool ATOMIC>
__global__ __launch_bounds__(512, 2)
void gemm_mfma(const short* __restrict__ A, const float* __restrict__ W,
               float* __restrict__ C, int lda, int ldb, int ldc, int kc) {
    const int bn0 = blockIdx.x * 64;
    const int k0  = blockIdx.z * kc;
    const int t = threadIdx.x;
    const int lane = t & 63;
    const int w = t >> 6;
    const int wm = w >> 1, wn = w & 1;
    const int fr = lane & 15, fg = lane >> 4;

    __shared__ __align__(16) char lds[2][16384];

    // B staging: 1024 16B-slots (row s>>4, slot s&15), 2 per thread
    const float* bp[2]; int bo[2];
    #pragma unroll
    for (int i = 0; i < 2; ++i) {
        int s = t + 512 * i, r = s >> 4, sl = s & 15;
        bp[i] = W + (size_t)(bn0 + r) * ldb + k0 + sl * 8;
        bo[i] = r * 256 + ((sl * 16) ^ ((r & 15) << 4));
    }
    // B fragment read bases: row = wn*32 + n*16 + fr; col byte = ks*64 + fg*16
    int brbase[2], brmask[2];
    #pragma unroll
    for (int n = 0; n < 2; ++n) {
        int row = wn * 32 + n * 16 + fr;
        brbase[n] = row * 256;
        brmask[n] = (row & 15) << 4;
    }
    // A fragment pointers (global, L2-hot): row = wm*64 + m*16 + fr
    const short* Afp[4];
    #pragma unroll
    for (int m = 0; m < 4; ++m)
        Afp[m] = A + (size_t)(wm * 64 + m * 16 + fr) * lda + k0 + fg * 8;

    f32x4 acc[4][2] = {};
    float4 rb[2][2];

    #define LOADB(kt) { const int ko = (kt) << 7;                                  \
        _Pragma("unroll") for (int i = 0; i < 2; ++i) {                            \
            rb[i][0] = *(const float4*)(bp[i] + ko);                               \
            rb[i][1] = *(const float4*)(bp[i] + ko + 4); } }
    #define STAGEB(buf) {                                                          \
        _Pragma("unroll") for (int i = 0; i < 2; ++i)                              \
            *(short8*)(lds[buf] + bo[i]) = cvt8(rb[i][0], rb[i][1]); }

    LOADB(0);
    STAGEB(0);
    int cur = 0;
    const int nT = kc >> 7;
    for (int kt = 0; kt < nT; ++kt) {
        __syncthreads();                       // B[cur] visible; prior reads done
        // A frags for THIS step (issued first -> MFMA waits only these)
        short8 af[4][4];
        #pragma unroll
        for (int m = 0; m < 4; ++m)
            #pragma unroll
            for (int ks = 0; ks < 4; ++ks)
                af[m][ks] = *(const short8*)(Afp[m] + (kt << 7) + ks * 32);
        if (kt + 1 < nT) LOADB(kt + 1);        // HBM prefetch, drains at STAGEB
        #pragma unroll
        for (int ks = 0; ks < 4; ++ks) {
            short8 bf[2];
            #pragma unroll
            for (int n = 0; n < 2; ++n)
                bf[n] = *(short8*)(lds[cur] + brbase[n] + ((ks * 64 + fg * 16) ^ brmask[n]));
            #pragma unroll
            for (int m = 0; m < 4; ++m)
                #pragma unroll
                for (int n = 0; n < 2; ++n)
                    acc[m][n] = __builtin_amdgcn_mfma_f32_16x16x32_bf16(af[m][ks], bf[n], acc[m][n], 0, 0, 0);
        }
        if (kt + 1 < nT) STAGEB(cur ^ 1);
        cur ^= 1;
    }
    #pragma unroll
    for (int m = 0; m < 4; ++m)
        #pragma unroll
        for (int n = 0; n < 2; ++n) {
            const int row = wm * 64 + m * 16 + fg * 4;
            const int col = bn0 + wn * 32 + n * 16 + fr;
            #pragma unroll
            for (int j = 0; j < 4; ++j) {
                if (ATOMIC)
                    unsafeAtomicAdd(&C[(size_t)(row + j) * ldc + col], acc[m][n][j]);
                else
                    C[(size_t)(row + j) * ldc + col] = acc[m][n][j];
            }
        }
    #undef LOADB
    #undef STAGEB
}

// ---------- fused middle: conv+silu -> scalars -> SSM -> gate+RMSNorm ----------
// One block per batch element (256 blocks x 1024 thr, 1/CU). xBC, y in LDS.
__global__ __launch_bounds__(1024)
void fused_mid(const float* __restrict__ zx, const float* __restrict__ conv_state,
               const float* __restrict__ conv_w, const float* __restrict__ conv_b,
               const float* __restrict__ dt_bias, const float* __restrict__ A_log,
               const float* __restrict__ ssm, const float* __restrict__ Dp,
               const float* __restrict__ nw, short* __restrict__ yn) {
    const int b = blockIdx.x, t = threadIdx.x;
    const int lane = t & 63, w = t >> 6;            // 16 waves
    __shared__ float sxbc[CONVDIM];
    __shared__ float sy[DINNER];
    __shared__ float sred[16];
    __shared__ float sdA[NHEADS_], scoef[NHEADS_];

    // ---- phase 1: conv + silu ----
    #pragma unroll
    for (int it = 0; it < 5; ++it) {
        int c = it * 1024 + t;
        if (c < CONVDIM) {
            float4 cs = *(const float4*)&conv_state[((size_t)b * CONVDIM + c) * 4];
            float4 w4 = *(const float4*)&conv_w[c * 4];
            float xin = zx[(size_t)b * DINPROJ + DINNER + c];
            float v = cs.y * w4.x + cs.z * w4.y + cs.w * w4.z + xin * w4.w + conv_b[c];
            sxbc[c] = v / (1.f + expf(-v));
        }
    }
    __syncthreads();

    // ---- phase 2: BC = B.C ; per-head dt, dA, coef ----
    if (t < 128) {
        float prod = sxbc[DINNER + t] * sxbc[DINNER + DSTATE + t];
        #pragma unroll
        for (int m = 1; m < 64; m <<= 1) prod += __shfl_xor(prod, m);
        if ((t & 63) == 0) sred[t >> 6] = prod;
    }
    __syncthreads();
    if (t < NHEADS_) {
        float BC = sred[0] + sred[1];
        float x = zx[(size_t)b * DINPROJ + DINNER + CONVDIM + t] + dt_bias[t];
        float dt = (x > 20.f) ? x : log1pf(expf(x));
        sdA[t] = expf(dt * (-expf(A_log[t])));
        scoef[t] = dt * BC + Dp[t];
    }
    __syncthreads();

    // ---- phase 3: SSM, contiguous-1KB-per-instr + 16-lane shuffle reduce ----
    {
        const int pq = lane >> 4, nl = lane & 15;
        const float4 c4a = *(const float4*)&sxbc[DINNER + DSTATE + nl * 8];
        const float4 c4b = *(const float4*)&sxbc[DINNER + DSTATE + nl * 8 + 4];
        #pragma unroll
        for (int k = 0; k < 4; ++k) {
            const int h = w * 4 + k;
            const float* S = ssm + (((size_t)b * NHEADS_ + h) * HEADDIM_) * DSTATE;
            const float dA = sdA[h], coef = scoef[h];
            #pragma unroll 8
            for (int pp = 0; pp < 16; ++pp) {
                const int p = pp * 4 + pq;
                float4 sa = *(const float4*)&S[p * DSTATE + nl * 8];
                float4 sb = *(const float4*)&S[p * DSTATE + nl * 8 + 4];
                float dot = sa.x * c4a.x + sa.y * c4a.y + sa.z * c4a.z + sa.w * c4a.w
                          + sb.x * c4b.x + sb.y * c4b.y + sb.z * c4b.z + sb.w * c4b.w;
                #pragma unroll
                for (int m = 1; m < 16; m <<= 1) dot += __shfl_xor(dot, m);
                if (nl == 0)
                    sy[h * HEADDIM_ + p] = dA * dot + sxbc[h * HEADDIM_ + p] * coef;
            }
        }
    }
    __syncthreads();

    // ---- phase 4: gate with silu(z), RMSNorm, -> bf16 ----
    {
        const int i = t * 4;
        float4 yv = *(const float4*)&sy[i];
        float4 zv = *(const float4*)&zx[(size_t)b * DINPROJ + i];
        float4 g;
        g.x = yv.x * (zv.x / (1.f + expf(-zv.x)));
        g.y = yv.y * (zv.y / (1.f + expf(-zv.y)));
        g.z = yv.z * (zv.z / (1.f + expf(-zv.z)));
        g.w = yv.w * (zv.w / (1.f + expf(-zv.w)));
        float ss = g.x * g.x + g.y * g.y + g.z * g.z + g.w * g.w;
        #pragma unroll
        for (int m = 1; m < 64; m <<= 1) ss += __shfl_xor(ss, m);
        __syncthreads();
        if (lane == 0) sred[w] = ss;
        __syncthreads();
        float tot = 0.f;
        #pragma unroll
        for (int k = 0; k < 16; ++k) tot += sred[k];
        const float sc = rsqrtf(tot * (1.f / DINNER) + EPS_);
        float4 w4 = *(const float4*)&nw[i];
        short4v o;
        o[0] = bfbits(g.x * sc * w4.x); o[1] = bfbits(g.y * sc * w4.y);
        o[2] = bfbits(g.z * sc * w4.z); o[3] = bfbits(g.w * sc * w4.w);
        *(short4v*)&yn[(size_t)b * DINNER + i] = o;
    }
}

extern "C" void kernel_launch(void* const* d_in, const int* in_sizes, int n_in,
                              void* d_out, int out_size, void* d_ws, size_t ws_size,
                              hipStream_t stream) {
    const float* hid        = (const float*)d_in[0];
    const float* conv_state = (const float*)d_in[1];
    const float* ssm        = (const float*)d_in[2];
    const float* W_in       = (const float*)d_in[3];
    const float* conv_w     = (const float*)d_in[4];
    const float* conv_b     = (const float*)d_in[5];
    const float* dt_bias    = (const float*)d_in[6];
    const float* A_log      = (const float*)d_in[7];
    const float* Dp         = (const float*)d_in[8];
    const float* norm_w     = (const float*)d_in[9];
    const float* W_out      = (const float*)d_in[10];
    float* out = (float*)d_out;

    float* ws    = (float*)d_ws;
    float* zx    = ws;                                  // 256*8512 f32
    short* hidbf = (short*)(zx + (size_t)BATCH * DINPROJ);   // 256*2048 bf16
    short* yn_bf = hidbf + (size_t)BATCH * DMODEL;      // 256*4096 bf16

    // 0) zero d_out (atomic-accumulate target) + hid -> bf16
    hipMemsetAsync(d_out, 0, (size_t)out_size * sizeof(float), stream);
    f2b<<<dim3(BATCH * DMODEL / 2048), 256, 0, stream>>>(hid, hidbf);
    // 1) zxbcdt = h @ W_in^T  (N=8512, K=2048): 133 blocks, W_in read once
    gemm_mfma<false><<<dim3(DINPROJ / 64, 1, 1), 512, 0, stream>>>(
        hidbf, W_in, zx, DMODEL, DMODEL, DINPROJ, DMODEL);
    // 2) fused conv/scalars/SSM/gate-norm: 256 blocks = 1 per CU
    fused_mid<<<dim3(BATCH), 1024, 0, stream>>>(
        zx, conv_state, conv_w, conv_b, dt_bias, A_log, ssm, Dp, norm_w, yn_bf);
    // 3) out = yn @ W_out^T  (N=2048, K=4096): split-K x8 -> 256 blocks,
    //    atomic accumulate into out (no partial buffer, no reduce kernel)
    gemm_mfma<true><<<dim3(DMODEL / 64, 1, 8), 512, 0, stream>>>(
        yn_bf, W_out, out, DINNER, DINNER, DMODEL, DINNER / 8);
}